// Round 18
// baseline (161.098 us; speedup 1.0000x reference)
//
#include <hip/hip_runtime.h>
#include <hip/hip_bf16.h>

typedef __bf16 bf16;
typedef __bf16 bf16x8 __attribute__((ext_vector_type(8)));
typedef float f32x4 __attribute__((ext_vector_type(4)));
typedef unsigned short u16;
typedef u16 u16x4 __attribute__((ext_vector_type(4)));

#define MFMA16(a, b, c) __builtin_amdgcn_mfma_f32_16x16x32_bf16(a, b, c, 0, 0, 0)
#define LOG2E 1.44269504f

// ---- problem constants ----
// B=8, T_NEW=128, E=1024, H=16, HD=64, NB=10, TPREV=4096, T=4224
// KVBLK=32: 12 chunks x 11 tiles (352 keys each); attn grid 1536 (XCD-swizzled).
// R16 structure (separate convert/ln, 8-wave GEMMs) + R17's attn XCD swizzle.
static __device__ __forceinline__ bf16x8 cvt8(float4 a, float4 b) {
  union { bf16 h[8]; bf16x8 v; } u;
  u.h[0] = (bf16)a.x; u.h[1] = (bf16)a.y; u.h[2] = (bf16)a.z; u.h[3] = (bf16)a.w;
  u.h[4] = (bf16)b.x; u.h[5] = (bf16)b.y; u.h[6] = (bf16)b.z; u.h[7] = (bf16)b.w;
  return u.v;
}

// ============ LayerNorm: X (1024 rows x 1024) f32 -> Xn bf16 ============
__global__ __launch_bounds__(256) void k_ln(const float* __restrict__ X,
                                            const float* __restrict__ g,
                                            const float* __restrict__ bb,
                                            bf16* __restrict__ Xn) {
  int m = blockIdx.x, t = threadIdx.x;
  const float* row = X + (size_t)m * 1024;
  float4 x = ((const float4*)row)[t];
  float s1 = x.x + x.y + x.z + x.w;
  float s2 = x.x * x.x + x.y * x.y + x.z * x.z + x.w * x.w;
#pragma unroll
  for (int off = 1; off < 64; off <<= 1) {
    s1 += __shfl_xor(s1, off);
    s2 += __shfl_xor(s2, off);
  }
  __shared__ float ws1[4], ws2[4];
  int w = t >> 6;
  if ((t & 63) == 0) { ws1[w] = s1; ws2[w] = s2; }
  __syncthreads();
  s1 = ws1[0] + ws1[1] + ws1[2] + ws1[3];
  s2 = ws2[0] + ws2[1] + ws2[2] + ws2[3];
  float mu = s1 * (1.f / 1024.f);
  float var = s2 * (1.f / 1024.f) - mu * mu;
  float rstd = rsqrtf(var + 1e-5f);
  float4 gg = ((const float4*)g)[t];
  float4 bv = ((const float4*)bb)[t];
  union { bf16 h[4]; u16x4 v; } u;
  u.h[0] = (bf16)((x.x - mu) * rstd * gg.x + bv.x);
  u.h[1] = (bf16)((x.y - mu) * rstd * gg.y + bv.y);
  u.h[2] = (bf16)((x.z - mu) * rstd * gg.z + bv.z);
  u.h[3] = (bf16)((x.w - mu) * rstd * gg.w + bv.w);
  ((u16x4*)(Xn + (size_t)m * 1024))[t] = u.v;
}

// ============ weight convert+transpose ============
__global__ __launch_bounds__(256) void k_convert(const float* __restrict__ Wq,
                                                 const float* __restrict__ Wk,
                                                 const float* __restrict__ Wv,
                                                 const float* __restrict__ Wr,
                                                 const float* __restrict__ Wp,
                                                 bf16* __restrict__ Wt_all,
                                                 bf16* __restrict__ Wpt) {
  __shared__ float tile[64][65];
  int t = threadIdx.x;
  int bn = blockIdx.x / 16, bk = blockIdx.x % 16;
  int n0 = bn * 64, k0 = bk * 64;
#pragma unroll
  for (int it = 0; it < 16; ++it) {
    int idx = t + 256 * it;
    int kl = idx >> 6, nl = idx & 63;
    int n = n0 + nl, k = k0 + kl;
    float v;
    if (n < 1024)       v = Wq[(size_t)k * 1024 + n];
    else if (n < 2048)  v = Wk[(size_t)k * 1024 + (n - 1024)];
    else if (n < 3072)  v = Wv[(size_t)k * 1024 + (n - 2048)];
    else if (n < 3232)  v = Wr[(size_t)k * 160 + (n - 3072)];
    else if (n < 3328)  v = 0.f;
    else                v = Wp[(size_t)k * 1024 + (n - 3328)];
    tile[kl][nl] = v;
  }
  __syncthreads();
#pragma unroll
  for (int it = 0; it < 16; ++it) {
    int idx = t + 256 * it;
    int nl = idx >> 6, kl = idx & 63;
    int n = n0 + nl, k = k0 + kl;
    bf16 v = (bf16)tile[kl][nl];
    if (n < 3328) Wt_all[(size_t)n * 1024 + k] = v;
    else          Wpt[(size_t)(n - 3328) * 1024 + k] = v;
  }
}

// ============ GEMM: C[m][n] = sum_k A[m][k]*Wt[n][k], K=1024 ============
// 512 threads / 8 waves per 128x128 tile; wave (wr,wc) owns 32x64 sub-tile.
template <int MODE>
__global__ __launch_bounds__(512) void k_gemm(const bf16* __restrict__ A,
                                              const bf16* __restrict__ Bw,
                                              bf16* __restrict__ Qb, bf16* __restrict__ Kn,
                                              bf16* __restrict__ Vn, float* __restrict__ Rws,
                                              const float* __restrict__ bq,
                                              const float* __restrict__ br,
                                              float* __restrict__ Out,
                                              const float* __restrict__ bproj,
                                              const float* __restrict__ Xres) {
  __shared__ __align__(16) bf16 As[128][72];
  __shared__ __align__(16) bf16 Bs[128][72];
  int t = threadIdx.x, l = t & 63, wid = t >> 6;   // 8 waves
  int ln = l & 15, grp = l >> 4;
  int m0 = blockIdx.y * 128, n0 = blockIdx.x * 128;
  int wr = wid >> 1, wc = wid & 1;                 // wr 0..3, wc 0..1
  f32x4 acc[2][4] = {};
  int srow = t >> 2, sq = (t & 3) * 16;            // 16 bf16 per thread per matrix

  for (int kt = 0; kt < 16; ++kt) {
    int k0 = kt * 64;
    const bf16* asrc = A + (size_t)(m0 + srow) * 1024 + k0 + sq;
    const bf16* bsrc = Bw + (size_t)(n0 + srow) * 1024 + k0 + sq;
    bf16x8 a0 = ((const bf16x8*)asrc)[0], a1 = ((const bf16x8*)asrc)[1];
    bf16x8 b0 = ((const bf16x8*)bsrc)[0], b1 = ((const bf16x8*)bsrc)[1];
    __syncthreads();
    *(bf16x8*)&As[srow][sq + 0] = a0;  *(bf16x8*)&As[srow][sq + 8] = a1;
    *(bf16x8*)&Bs[srow][sq + 0] = b0;  *(bf16x8*)&Bs[srow][sq + 8] = b1;
    __syncthreads();
#pragma unroll
    for (int ks = 0; ks < 2; ++ks) {
      int kk = ks * 32 + grp * 8;
      bf16x8 af[2], bf[4];
#pragma unroll
      for (int is = 0; is < 2; ++is) af[is] = *(const bf16x8*)&As[wr * 32 + is * 16 + ln][kk];
#pragma unroll
      for (int js = 0; js < 4; ++js) bf[js] = *(const bf16x8*)&Bs[wc * 64 + js * 16 + ln][kk];
#pragma unroll
      for (int is = 0; is < 2; ++is)
#pragma unroll
        for (int js = 0; js < 4; ++js) acc[is][js] = MFMA16(af[is], bf[js], acc[is][js]);
    }
  }

#pragma unroll
  for (int is = 0; is < 2; ++is)
#pragma unroll
    for (int js = 0; js < 4; ++js)
#pragma unroll
      for (int r = 0; r < 4; ++r) {
        int m = m0 + wr * 32 + is * 16 + grp * 4 + r;
        int n = n0 + wc * 64 + js * 16 + ln;
        float v = acc[is][js][r];
        if (MODE == 0) {
          int b = m >> 7, il = m & 127;
          if (n < 1024) {
            int h = n >> 6, dm = n & 63;
            Qb[((size_t)(b * 16 + h) * 128 + il) * 64 + dm] = (bf16)((v + bq[n]) * (0.125f * LOG2E));
          } else if (n < 2048) {
            Kn[(size_t)m * 1024 + (n - 1024)] = (bf16)v;
          } else if (n < 3072) {
            Vn[(size_t)m * 1024 + (n - 2048)] = (bf16)v;
          } else if (n < 3232) {
            int e = n - 3072, hh = e / 10, nb = e - hh * 10;
            Rws[((size_t)(b * 16 + hh) * 128 + il) * 10 + nb] = v + br[e];
          }
        } else {
          Out[(size_t)m * 1024 + n] = v + bproj[n] + Xres[(size_t)m * 1024 + n];
        }
      }
}

// ============ attention: grid = 1536 (XCD-swizzled), 512 threads ============
// KVBLK=32, 11 tiles/chunk. Swapped-QK in-register softmax; chunk bnd table;
// sigma key-permute PV; defer-max; dbuf K/V, 1 barrier/tile.
__global__ __launch_bounds__(512, 4) void k_attn(const float* __restrict__ cacheK,
                                                 const float* __restrict__ cacheV,
                                                 const bf16* __restrict__ Kn,
                                                 const bf16* __restrict__ Vn,
                                                 const bf16* __restrict__ Qb,
                                                 const float* __restrict__ Rws,
                                                 const float* __restrict__ bnd,
                                                 bf16* __restrict__ Opart,
                                                 float* __restrict__ mws,
                                                 float* __restrict__ lws) {
  __shared__ __align__(16) bf16 Ks[2][32][72];   //  9216 B
  __shared__ __align__(16) bf16 Vt[2][64][36];   //  9216 B  Vt[p][d][sigma(j)]
  __shared__ __align__(16) bf16 Gw[8][48][20];   // 15360 B  per-wave G window
  __shared__ __align__(16) bf16 bTf[516][16];    // 16512 B  chunk-wide bnd: [q][n]

  int t = threadIdx.x, l = t & 63, w = t >> 6;
  int grp = l >> 4, ln = l & 15;
  // XCD-aware bijective swizzle (nwg=1536, 8 XCDs): same-XCD blocks share a
  // contiguous bh range -> Qb/Rws/Kn/Vn slices L2-local per XCD.
  int sw = (blockIdx.x & 7) * 192 + (blockIdx.x >> 3);
  int s = sw % 12, bh = sw / 12;
  int b = bh >> 4, h = bh & 15;
  int jbase = s * 352;
  int dlo0 = 4033 - jbase;

  // ---- chunk prologue: stage bnd window bTf[q][n] = bnd[n][dlo0-320+q] ----
  {
    int q = t;
    int d = dlo0 - 320 + q;
    d = d < 0 ? 0 : (d > 4095 ? 4095 : d);
#pragma unroll
    for (int n = 0; n < 10; ++n) bTf[q][n] = (bf16)bnd[(size_t)n * 4096 + d];
#pragma unroll
    for (int n = 10; n < 16; ++n) bTf[q][n] = (bf16)0.f;
  }
  if (t < 4) {
#pragma unroll
    for (int n = 0; n < 16; ++n) bTf[512 + t][n] = (bf16)0.f;
  }

  int iq = w * 16 + ln;        // this lane's q-row
  bf16x8 qf[2];
  qf[0] = *(const bf16x8*)(Qb + ((size_t)bh * 128 + iq) * 64 + grp * 8);
  qf[1] = *(const bf16x8*)(Qb + ((size_t)bh * 128 + iq) * 64 + 32 + grp * 8);
  bf16x8 rf;
  {
    union { bf16 hh[8]; bf16x8 v; } u;
    const float* rrow = Rws + ((size_t)bh * 128 + iq) * 10;
#pragma unroll
    for (int e = 0; e < 8; ++e) {
      int k = grp * 8 + e;
      u.hh[e] = (bf16)(k < 10 ? rrow[k] * LOG2E : 0.f);
    }
    rf = u.v;
  }

  // staging thread roles (32-key tile)
  int krow = t >> 4, kcb = (t & 15) * 4;        // K: 32 rows x 16 col-blocks of 4
  int vjl = t & 31, vd0 = (t >> 5) * 4;         // V: 32 j x 16 d-blocks of 4
  // sigma(j) = grp(j)*8 + js(j)*4 + r(j)  (bit permute, j<32)
  int vsp = (((vjl >> 2) & 3) << 3) | (((vjl >> 4) & 1) << 2) | (vjl & 3);

  float4 kA, vA;

  auto issue = [&](int jt0) {
    if (jt0 < 4096) {
      kA = *(const float4*)(cacheK + ((size_t)(b * 4096 + jt0 + krow)) * 1024 + h * 64 + kcb);
      vA = *(const float4*)(cacheV + ((size_t)(b * 4096 + jt0 + vjl)) * 1024 + h * 64 + vd0);
    } else {
      u16x4 kN = *(const u16x4*)(Kn + ((size_t)(b * 128 + (jt0 + krow - 4096))) * 1024 + h * 64 + kcb);
      u16x4 vN = *(const u16x4*)(Vn + ((size_t)(b * 128 + (jt0 + vjl - 4096))) * 1024 + h * 64 + vd0);
      union { u16 u; bf16 h; } c;
      c.u = kN[0]; kA.x = (float)c.h; c.u = kN[1]; kA.y = (float)c.h;
      c.u = kN[2]; kA.z = (float)c.h; c.u = kN[3]; kA.w = (float)c.h;
      c.u = vN[0]; vA.x = (float)c.h; c.u = vN[1]; vA.y = (float)c.h;
      c.u = vN[2]; vA.z = (float)c.h; c.u = vN[3]; vA.w = (float)c.h;
    }
  };
  auto stage = [&](int p) {
    union { bf16 hh[4]; u16x4 v; } ku;
    ku.hh[0] = (bf16)kA.x; ku.hh[1] = (bf16)kA.y;
    ku.hh[2] = (bf16)kA.z; ku.hh[3] = (bf16)kA.w;
    *(u16x4*)&Ks[p][krow][kcb] = ku.v;
    Vt[p][vd0 + 0][vsp] = (bf16)vA.x; Vt[p][vd0 + 1][vsp] = (bf16)vA.y;
    Vt[p][vd0 + 2][vsp] = (bf16)vA.z; Vt[p][vd0 + 3][vsp] = (bf16)vA.w;
  };

  issue(jbase);
  stage(0);
  issue(jbase + 32);

  f32x4 Oacc[4] = {};
  float m_r = -1e30f, l_r = 0.f;

  for (int tt = 0; tt < 11; ++tt) {
    int jt0 = jbase + tt * 32;
    int cur = tt & 1;
    __syncthreads();
    if (tt + 1 < 11) stage(cur ^ 1);
    if (tt + 2 < 11) issue(jbase + (tt + 2) * 32);

    // ---- S^T = K @ Q^T : lane holds S[j=js*16+grp*4+r][i=ln] ----
    __builtin_amdgcn_s_setprio(1);
    f32x4 Sacc[2] = {};
#pragma unroll
    for (int ks = 0; ks < 2; ++ks) {
      int kk = ks * 32 + grp * 8;
#pragma unroll
      for (int js = 0; js < 2; ++js) {
        bf16x8 bfr = *(const bf16x8*)&Ks[cur][js * 16 + ln][kk];
        Sacc[js] = MFMA16(bfr, qf[ks], Sacc[js]);
      }
    }
    // ---- per-wave G window (47 c's): rows qb + w*16 + u*16 + ln ----
    int qb = 352 - 32 * tt;
#pragma unroll
    for (int u = 0; u < 3; ++u) {
      bf16x8 bfr = *(const bf16x8*)&bTf[qb + w * 16 + u * 16 + ln][grp * 8];
      f32x4 z = {};
      f32x4 g = MFMA16(rf, bfr, z);
      union { bf16 hh[4]; u16x4 v; } uu;
      uu.hh[0] = (bf16)g[0]; uu.hh[1] = (bf16)g[1];
      uu.hh[2] = (bf16)g[2]; uu.hh[3] = (bf16)g[3];
      *(u16x4*)&Gw[w][u * 16 + ln][grp * 4] = uu.v;
    }
    __builtin_amdgcn_s_setprio(0);

    // ---- fold G (+mask only on boundary tiles); in-lane row max ----
    float mx = -1e30f;
    if (jt0 >= 128 && jt0 < 4066) {
#pragma unroll
      for (int js = 0; js < 2; ++js)
#pragma unroll
        for (int r = 0; r < 4; ++r) {
          int jj = js * 16 + grp * 4 + r;
          int cl = ln - jj + 31;           // in [0,47)
          float v = Sacc[js][r] + (float)Gw[w][cl][ln];
          Sacc[js][r] = v;
          mx = fmaxf(mx, v);
        }
    } else {
#pragma unroll
      for (int js = 0; js < 2; ++js)
#pragma unroll
        for (int r = 0; r < 4; ++r) {
          int jj = js * 16 + grp * 4 + r;
          int d = 4096 + iq - (jt0 + jj);
          bool valid = ((unsigned)d) < 4096u;
          int cl = ln - jj + 31;
          float g = (float)Gw[w][cl][ln];
          float v = valid ? (Sacc[js][r] + g) : -1e9f;
          Sacc[js][r] = v;
          mx = fmaxf(mx, v);
        }
    }
    mx = fmaxf(mx, __shfl_xor(mx, 16));
    mx = fmaxf(mx, __shfl_xor(mx, 32));

    // ---- defer-max: rescale only when max grew by > 8 (log2 domain) ----
    if (!__all(mx <= m_r + 8.f)) {
      float mnew = fmaxf(m_r, mx);
      float scn = exp2f(m_r - mnew);
      m_r = mnew;
      l_r *= scn;
#pragma unroll
      for (int r = 0; r < 4; ++r) {
        float scr = __shfl(scn, grp * 4 + r, 16);
#pragma unroll
        for (int ds = 0; ds < 4; ++ds) Oacc[ds][r] *= scr;
      }
    }

    // ---- P = exp2(S - m), packed in-lane as the PV A-frag (sigma order) ----
    union { bf16 hh[8]; bf16x8 v; } p0;
    float rsl = 0.f;
#pragma unroll
    for (int js = 0; js < 2; ++js)
#pragma unroll
      for (int r = 0; r < 4; ++r) {
        float p = exp2f(Sacc[js][r] - m_r);
        rsl += p;
        p0.hh[js * 4 + r] = (bf16)p;     // k-slot e = js*4 + r
      }
    l_r += rsl;

    // ---- O += P @ V : one K=32 MFMA per d-tile ----
    __builtin_amdgcn_s_setprio(1);
#pragma unroll
    for (int ds = 0; ds < 4; ++ds) {
      bf16x8 v0 = *(const bf16x8*)&Vt[cur][ds * 16 + ln][grp * 8];
      Oacc[ds] = MFMA16(p0.v, v0, Oacc[ds]);
    }
    __builtin_amdgcn_s_setprio(0);
  }

  // epilogue: finish l reduction across grp copies (rows = ln)
  l_r += __shfl_xor(l_r, 16);
  l_r += __shfl_xor(l_r, 32);

  int part = s * 128 + bh;
#pragma unroll
  for (int ds = 0; ds < 4; ++ds)
#pragma unroll
    for (int r = 0; r < 4; ++r) {
      int il = w * 16 + grp * 4 + r;
      Opart[((size_t)part * 128 + il) * 64 + ds * 16 + ln] = (bf16)Oacc[ds][r];
    }
  if (grp == 0) {
    mws[(size_t)part * 128 + iq] = m_r;
    lws[(size_t)part * 128 + iq] = l_r;
  }
}

// ============ split-K combine over 12 parts (LDS-staged m/l, exp2 domain) ============
__global__ __launch_bounds__(256) void k_combine(const bf16* __restrict__ Opart,
                                                 const float* __restrict__ mws,
                                                 const float* __restrict__ lws,
                                                 bf16* __restrict__ Aout) {
  __shared__ float msh[12][32], lsh[12][32];
  int bh = blockIdx.x, q = blockIdx.y, t = threadIdx.x;
  int b = bh >> 4, h = bh & 15;
  for (int idx = t; idx < 384; idx += 256) {
    int s = idx >> 5, io = idx & 31;
    msh[s][io] = mws[(size_t)(s * 128 + bh) * 128 + q * 32 + io];
    lsh[s][io] = lws[(size_t)(s * 128 + bh) * 128 + q * 32 + io];
  }
  __syncthreads();
  int dm = t & 63, i4 = t >> 6;
  for (int ii = 0; ii < 8; ++ii) {
    int io = i4 * 8 + ii;
    int i = q * 32 + io;
    float M = -1e30f;
#pragma unroll
    for (int s = 0; s < 12; ++s) M = fmaxf(M, msh[s][io]);
    float L = 0.f, acc = 0.f;
#pragma unroll
    for (int s = 0; s < 12; ++s) {
      float wgt = exp2f(msh[s][io] - M);
      L += wgt * lsh[s][io];
      acc += wgt * (float)Opart[((size_t)(s * 128 + bh) * 128 + i) * 64 + dm];
    }
    Aout[((size_t)(b * 128 + i)) * 1024 + h * 64 + dm] = (bf16)(acc / L);
  }
}

extern "C" void kernel_launch(void* const* d_in, const int* in_sizes, int n_in,
                              void* d_out, int out_size, void* d_ws, size_t ws_size,
                              hipStream_t stream) {
  (void)in_sizes; (void)n_in; (void)out_size; (void)ws_size;
  const float* X      = (const float*)d_in[0];
  const float* cacheK = (const float*)d_in[1];
  const float* cacheV = (const float*)d_in[2];
  const float* Wq     = (const float*)d_in[3];
  const float* bq     = (const float*)d_in[4];
  const float* Wk     = (const float*)d_in[5];
  const float* Wv     = (const float*)d_in[6];
  const float* Wproj  = (const float*)d_in[7];
  const float* bproj  = (const float*)d_in[8];
  const float* Wr     = (const float*)d_in[9];
  const float* br     = (const float*)d_in[10];
  const float* bnd    = (const float*)d_in[11];
  const float* lng    = (const float*)d_in[12];
  const float* lnb    = (const float*)d_in[13];
  float* out = (float*)d_out;

  char* ws = (char*)d_ws;
  bf16* Wt_all = (bf16*)ws;  ws += (size_t)3328 * 1024 * 2;
  bf16* Wpt    = (bf16*)ws;  ws += (size_t)1024 * 1024 * 2;
  bf16* Xn     = (bf16*)ws;  ws += (size_t)1024 * 1024 * 2;
  bf16* Qb     = (bf16*)ws;  ws += (size_t)1024 * 1024 * 2;
  bf16* Kn     = (bf16*)ws;  ws += (size_t)1024 * 1024 * 2;
  bf16* Vn     = (bf16*)ws;  ws += (size_t)1024 * 1024 * 2;
  bf16* Aattn  = (bf16*)ws;  ws += (size_t)1024 * 1024 * 2;
  float* Rws   = (float*)ws; ws += (size_t)128 * 128 * 10 * 4;
  float* mws   = (float*)ws; ws += (size_t)12 * 128 * 128 * 4;
  float* lws   = (float*)ws; ws += (size_t)12 * 128 * 128 * 4;
  bf16* Opart  = (bf16*)ws;  ws += (size_t)12 * 128 * 128 * 64 * 2;

  k_convert<<<dim3(68 * 16), 256, 0, stream>>>(Wq, Wk, Wv, Wr, Wproj, Wt_all, Wpt);
  k_ln<<<dim3(1024), 256, 0, stream>>>(X, lng, lnb, Xn);
  k_gemm<0><<<dim3(26, 8), 512, 0, stream>>>(Xn, Wt_all, Qb, Kn, Vn, Rws, bq, br,
                                             nullptr, nullptr, nullptr);
  k_attn<<<dim3(1536), 512, 0, stream>>>(cacheK, cacheV, Kn, Vn, Qb, Rws, bnd,
                                         Opart, mws, lws);
  k_combine<<<dim3(128, 4), 256, 0, stream>>>(Opart, mws, lws, Aattn);
  k_gemm<1><<<dim3(8, 8), 512, 0, stream>>>(Aattn, Wpt, nullptr, nullptr, nullptr,
                                            nullptr, nullptr, nullptr, out, bproj, X);
}

// Round 19
// 153.404 us; speedup vs baseline: 1.0502x; 1.0502x over previous
//
#include <hip/hip_runtime.h>
#include <hip/hip_bf16.h>

typedef __bf16 bf16;
typedef __bf16 bf16x8 __attribute__((ext_vector_type(8)));
typedef float f32x4 __attribute__((ext_vector_type(4)));
typedef unsigned short u16;
typedef u16 u16x4 __attribute__((ext_vector_type(4)));

#define MFMA16(a, b, c) __builtin_amdgcn_mfma_f32_16x16x32_bf16(a, b, c, 0, 0, 0)
#define LOG2E 1.44269504f

// ---- problem constants ----
// B=8, T_NEW=128, E=1024, H=16, HD=64, NB=10, TPREV=4096, T=4224
// KVBLK=32: 12 chunks x 11 tiles (352 keys each); grid 1536.
// R16 configuration verbatim (best measured: 153.7 us total).
static __device__ __forceinline__ bf16x8 cvt8(float4 a, float4 b) {
  union { bf16 h[8]; bf16x8 v; } u;
  u.h[0] = (bf16)a.x; u.h[1] = (bf16)a.y; u.h[2] = (bf16)a.z; u.h[3] = (bf16)a.w;
  u.h[4] = (bf16)b.x; u.h[5] = (bf16)b.y; u.h[6] = (bf16)b.z; u.h[7] = (bf16)b.w;
  return u.v;
}

// ============ LayerNorm: X (1024 rows x 1024) f32 -> Xn bf16 ============
__global__ __launch_bounds__(256) void k_ln(const float* __restrict__ X,
                                            const float* __restrict__ g,
                                            const float* __restrict__ bb,
                                            bf16* __restrict__ Xn) {
  int m = blockIdx.x, t = threadIdx.x;
  const float* row = X + (size_t)m * 1024;
  float4 x = ((const float4*)row)[t];
  float s1 = x.x + x.y + x.z + x.w;
  float s2 = x.x * x.x + x.y * x.y + x.z * x.z + x.w * x.w;
#pragma unroll
  for (int off = 1; off < 64; off <<= 1) {
    s1 += __shfl_xor(s1, off);
    s2 += __shfl_xor(s2, off);
  }
  __shared__ float ws1[4], ws2[4];
  int w = t >> 6;
  if ((t & 63) == 0) { ws1[w] = s1; ws2[w] = s2; }
  __syncthreads();
  s1 = ws1[0] + ws1[1] + ws1[2] + ws1[3];
  s2 = ws2[0] + ws2[1] + ws2[2] + ws2[3];
  float mu = s1 * (1.f / 1024.f);
  float var = s2 * (1.f / 1024.f) - mu * mu;
  float rstd = rsqrtf(var + 1e-5f);
  float4 gg = ((const float4*)g)[t];
  float4 bv = ((const float4*)bb)[t];
  union { bf16 h[4]; u16x4 v; } u;
  u.h[0] = (bf16)((x.x - mu) * rstd * gg.x + bv.x);
  u.h[1] = (bf16)((x.y - mu) * rstd * gg.y + bv.y);
  u.h[2] = (bf16)((x.z - mu) * rstd * gg.z + bv.z);
  u.h[3] = (bf16)((x.w - mu) * rstd * gg.w + bv.w);
  ((u16x4*)(Xn + (size_t)m * 1024))[t] = u.v;
}

// ============ weight convert+transpose ============
__global__ __launch_bounds__(256) void k_convert(const float* __restrict__ Wq,
                                                 const float* __restrict__ Wk,
                                                 const float* __restrict__ Wv,
                                                 const float* __restrict__ Wr,
                                                 const float* __restrict__ Wp,
                                                 bf16* __restrict__ Wt_all,
                                                 bf16* __restrict__ Wpt) {
  __shared__ float tile[64][65];
  int t = threadIdx.x;
  int bn = blockIdx.x / 16, bk = blockIdx.x % 16;
  int n0 = bn * 64, k0 = bk * 64;
#pragma unroll
  for (int it = 0; it < 16; ++it) {
    int idx = t + 256 * it;
    int kl = idx >> 6, nl = idx & 63;
    int n = n0 + nl, k = k0 + kl;
    float v;
    if (n < 1024)       v = Wq[(size_t)k * 1024 + n];
    else if (n < 2048)  v = Wk[(size_t)k * 1024 + (n - 1024)];
    else if (n < 3072)  v = Wv[(size_t)k * 1024 + (n - 2048)];
    else if (n < 3232)  v = Wr[(size_t)k * 160 + (n - 3072)];
    else if (n < 3328)  v = 0.f;
    else                v = Wp[(size_t)k * 1024 + (n - 3328)];
    tile[kl][nl] = v;
  }
  __syncthreads();
#pragma unroll
  for (int it = 0; it < 16; ++it) {
    int idx = t + 256 * it;
    int nl = idx >> 6, kl = idx & 63;
    int n = n0 + nl, k = k0 + kl;
    bf16 v = (bf16)tile[kl][nl];
    if (n < 3328) Wt_all[(size_t)n * 1024 + k] = v;
    else          Wpt[(size_t)(n - 3328) * 1024 + k] = v;
  }
}

// ============ GEMM: C[m][n] = sum_k A[m][k]*Wt[n][k], K=1024 ============
// 512 threads / 8 waves per 128x128 tile; wave (wr,wc) owns 32x64 sub-tile.
template <int MODE>
__global__ __launch_bounds__(512) void k_gemm(const bf16* __restrict__ A,
                                              const bf16* __restrict__ Bw,
                                              bf16* __restrict__ Qb, bf16* __restrict__ Kn,
                                              bf16* __restrict__ Vn, float* __restrict__ Rws,
                                              const float* __restrict__ bq,
                                              const float* __restrict__ br,
                                              float* __restrict__ Out,
                                              const float* __restrict__ bproj,
                                              const float* __restrict__ Xres) {
  __shared__ __align__(16) bf16 As[128][72];
  __shared__ __align__(16) bf16 Bs[128][72];
  int t = threadIdx.x, l = t & 63, wid = t >> 6;   // 8 waves
  int ln = l & 15, grp = l >> 4;
  int m0 = blockIdx.y * 128, n0 = blockIdx.x * 128;
  int wr = wid >> 1, wc = wid & 1;                 // wr 0..3, wc 0..1
  f32x4 acc[2][4] = {};
  int srow = t >> 2, sq = (t & 3) * 16;            // 16 bf16 per thread per matrix

  for (int kt = 0; kt < 16; ++kt) {
    int k0 = kt * 64;
    const bf16* asrc = A + (size_t)(m0 + srow) * 1024 + k0 + sq;
    const bf16* bsrc = Bw + (size_t)(n0 + srow) * 1024 + k0 + sq;
    bf16x8 a0 = ((const bf16x8*)asrc)[0], a1 = ((const bf16x8*)asrc)[1];
    bf16x8 b0 = ((const bf16x8*)bsrc)[0], b1 = ((const bf16x8*)bsrc)[1];
    __syncthreads();
    *(bf16x8*)&As[srow][sq + 0] = a0;  *(bf16x8*)&As[srow][sq + 8] = a1;
    *(bf16x8*)&Bs[srow][sq + 0] = b0;  *(bf16x8*)&Bs[srow][sq + 8] = b1;
    __syncthreads();
#pragma unroll
    for (int ks = 0; ks < 2; ++ks) {
      int kk = ks * 32 + grp * 8;
      bf16x8 af[2], bf[4];
#pragma unroll
      for (int is = 0; is < 2; ++is) af[is] = *(const bf16x8*)&As[wr * 32 + is * 16 + ln][kk];
#pragma unroll
      for (int js = 0; js < 4; ++js) bf[js] = *(const bf16x8*)&Bs[wc * 64 + js * 16 + ln][kk];
#pragma unroll
      for (int is = 0; is < 2; ++is)
#pragma unroll
        for (int js = 0; js < 4; ++js) acc[is][js] = MFMA16(af[is], bf[js], acc[is][js]);
    }
  }

#pragma unroll
  for (int is = 0; is < 2; ++is)
#pragma unroll
    for (int js = 0; js < 4; ++js)
#pragma unroll
      for (int r = 0; r < 4; ++r) {
        int m = m0 + wr * 32 + is * 16 + grp * 4 + r;
        int n = n0 + wc * 64 + js * 16 + ln;
        float v = acc[is][js][r];
        if (MODE == 0) {
          int b = m >> 7, il = m & 127;
          if (n < 1024) {
            int h = n >> 6, dm = n & 63;
            Qb[((size_t)(b * 16 + h) * 128 + il) * 64 + dm] = (bf16)((v + bq[n]) * (0.125f * LOG2E));
          } else if (n < 2048) {
            Kn[(size_t)m * 1024 + (n - 1024)] = (bf16)v;
          } else if (n < 3072) {
            Vn[(size_t)m * 1024 + (n - 2048)] = (bf16)v;
          } else if (n < 3232) {
            int e = n - 3072, hh = e / 10, nb = e - hh * 10;
            Rws[((size_t)(b * 16 + hh) * 128 + il) * 10 + nb] = v + br[e];
          }
        } else {
          Out[(size_t)m * 1024 + n] = v + bproj[n] + Xres[(size_t)m * 1024 + n];
        }
      }
}

// ============ attention: grid = 128 bh * 12 chunks, 512 threads ============
// KVBLK=32, 11 tiles/chunk. Swapped-QK in-register softmax; chunk-wide bnd
// table; sigma key-permute PV; defer-max; dbuf K/V, 1 barrier/tile.
__global__ __launch_bounds__(512, 4) void k_attn(const float* __restrict__ cacheK,
                                                 const float* __restrict__ cacheV,
                                                 const bf16* __restrict__ Kn,
                                                 const bf16* __restrict__ Vn,
                                                 const bf16* __restrict__ Qb,
                                                 const float* __restrict__ Rws,
                                                 const float* __restrict__ bnd,
                                                 bf16* __restrict__ Opart,
                                                 float* __restrict__ mws,
                                                 float* __restrict__ lws) {
  __shared__ __align__(16) bf16 Ks[2][32][72];   //  9216 B
  __shared__ __align__(16) bf16 Vt[2][64][36];   //  9216 B  Vt[p][d][sigma(j)]
  __shared__ __align__(16) bf16 Gw[8][48][20];   // 15360 B  per-wave G window
  __shared__ __align__(16) bf16 bTf[516][16];    // 16512 B  chunk-wide bnd: [q][n]

  int t = threadIdx.x, l = t & 63, w = t >> 6;
  int grp = l >> 4, ln = l & 15;
  int s = blockIdx.x % 12, bh = blockIdx.x / 12;
  int b = bh >> 4, h = bh & 15;
  int jbase = s * 352;
  int dlo0 = 4033 - jbase;

  // ---- chunk prologue: stage bnd window bTf[q][n] = bnd[n][dlo0-320+q] ----
  {
    int q = t;
    int d = dlo0 - 320 + q;
    d = d < 0 ? 0 : (d > 4095 ? 4095 : d);
#pragma unroll
    for (int n = 0; n < 10; ++n) bTf[q][n] = (bf16)bnd[(size_t)n * 4096 + d];
#pragma unroll
    for (int n = 10; n < 16; ++n) bTf[q][n] = (bf16)0.f;
  }
  if (t < 4) {
#pragma unroll
    for (int n = 0; n < 16; ++n) bTf[512 + t][n] = (bf16)0.f;
  }

  int iq = w * 16 + ln;        // this lane's q-row
  bf16x8 qf[2];
  qf[0] = *(const bf16x8*)(Qb + ((size_t)bh * 128 + iq) * 64 + grp * 8);
  qf[1] = *(const bf16x8*)(Qb + ((size_t)bh * 128 + iq) * 64 + 32 + grp * 8);
  bf16x8 rf;
  {
    union { bf16 hh[8]; bf16x8 v; } u;
    const float* rrow = Rws + ((size_t)bh * 128 + iq) * 10;
#pragma unroll
    for (int e = 0; e < 8; ++e) {
      int k = grp * 8 + e;
      u.hh[e] = (bf16)(k < 10 ? rrow[k] * LOG2E : 0.f);
    }
    rf = u.v;
  }

  // staging thread roles (32-key tile)
  int krow = t >> 4, kcb = (t & 15) * 4;        // K: 32 rows x 16 col-blocks of 4
  int vjl = t & 31, vd0 = (t >> 5) * 4;         // V: 32 j x 16 d-blocks of 4
  // sigma(j) = grp(j)*8 + js(j)*4 + r(j)  (bit permute, j<32)
  int vsp = (((vjl >> 2) & 3) << 3) | (((vjl >> 4) & 1) << 2) | (vjl & 3);

  float4 kA, vA;

  auto issue = [&](int jt0) {
    if (jt0 < 4096) {
      kA = *(const float4*)(cacheK + ((size_t)(b * 4096 + jt0 + krow)) * 1024 + h * 64 + kcb);
      vA = *(const float4*)(cacheV + ((size_t)(b * 4096 + jt0 + vjl)) * 1024 + h * 64 + vd0);
    } else {
      u16x4 kN = *(const u16x4*)(Kn + ((size_t)(b * 128 + (jt0 + krow - 4096))) * 1024 + h * 64 + kcb);
      u16x4 vN = *(const u16x4*)(Vn + ((size_t)(b * 128 + (jt0 + vjl - 4096))) * 1024 + h * 64 + vd0);
      union { u16 u; bf16 h; } c;
      c.u = kN[0]; kA.x = (float)c.h; c.u = kN[1]; kA.y = (float)c.h;
      c.u = kN[2]; kA.z = (float)c.h; c.u = kN[3]; kA.w = (float)c.h;
      c.u = vN[0]; vA.x = (float)c.h; c.u = vN[1]; vA.y = (float)c.h;
      c.u = vN[2]; vA.z = (float)c.h; c.u = vN[3]; vA.w = (float)c.h;
    }
  };
  auto stage = [&](int p) {
    union { bf16 hh[4]; u16x4 v; } ku;
    ku.hh[0] = (bf16)kA.x; ku.hh[1] = (bf16)kA.y;
    ku.hh[2] = (bf16)kA.z; ku.hh[3] = (bf16)kA.w;
    *(u16x4*)&Ks[p][krow][kcb] = ku.v;
    Vt[p][vd0 + 0][vsp] = (bf16)vA.x; Vt[p][vd0 + 1][vsp] = (bf16)vA.y;
    Vt[p][vd0 + 2][vsp] = (bf16)vA.z; Vt[p][vd0 + 3][vsp] = (bf16)vA.w;
  };

  issue(jbase);
  stage(0);
  issue(jbase + 32);

  f32x4 Oacc[4] = {};
  float m_r = -1e30f, l_r = 0.f;

  for (int tt = 0; tt < 11; ++tt) {
    int jt0 = jbase + tt * 32;
    int cur = tt & 1;
    __syncthreads();
    if (tt + 1 < 11) stage(cur ^ 1);
    if (tt + 2 < 11) issue(jbase + (tt + 2) * 32);

    // ---- S^T = K @ Q^T : lane holds S[j=js*16+grp*4+r][i=ln] ----
    __builtin_amdgcn_s_setprio(1);
    f32x4 Sacc[2] = {};
#pragma unroll
    for (int ks = 0; ks < 2; ++ks) {
      int kk = ks * 32 + grp * 8;
#pragma unroll
      for (int js = 0; js < 2; ++js) {
        bf16x8 bfr = *(const bf16x8*)&Ks[cur][js * 16 + ln][kk];
        Sacc[js] = MFMA16(bfr, qf[ks], Sacc[js]);
      }
    }
    // ---- per-wave G window (47 c's): rows qb + w*16 + u*16 + ln ----
    int qb = 352 - 32 * tt;
#pragma unroll
    for (int u = 0; u < 3; ++u) {
      bf16x8 bfr = *(const bf16x8*)&bTf[qb + w * 16 + u * 16 + ln][grp * 8];
      f32x4 z = {};
      f32x4 g = MFMA16(rf, bfr, z);
      union { bf16 hh[4]; u16x4 v; } uu;
      uu.hh[0] = (bf16)g[0]; uu.hh[1] = (bf16)g[1];
      uu.hh[2] = (bf16)g[2]; uu.hh[3] = (bf16)g[3];
      *(u16x4*)&Gw[w][u * 16 + ln][grp * 4] = uu.v;
    }
    __builtin_amdgcn_s_setprio(0);

    // ---- fold G (+mask only on boundary tiles); in-lane row max ----
    float mx = -1e30f;
    if (jt0 >= 128 && jt0 < 4066) {
#pragma unroll
      for (int js = 0; js < 2; ++js)
#pragma unroll
        for (int r = 0; r < 4; ++r) {
          int jj = js * 16 + grp * 4 + r;
          int cl = ln - jj + 31;           // in [0,47)
          float v = Sacc[js][r] + (float)Gw[w][cl][ln];
          Sacc[js][r] = v;
          mx = fmaxf(mx, v);
        }
    } else {
#pragma unroll
      for (int js = 0; js < 2; ++js)
#pragma unroll
        for (int r = 0; r < 4; ++r) {
          int jj = js * 16 + grp * 4 + r;
          int d = 4096 + iq - (jt0 + jj);
          bool valid = ((unsigned)d) < 4096u;
          int cl = ln - jj + 31;
          float g = (float)Gw[w][cl][ln];
          float v = valid ? (Sacc[js][r] + g) : -1e9f;
          Sacc[js][r] = v;
          mx = fmaxf(mx, v);
        }
    }
    mx = fmaxf(mx, __shfl_xor(mx, 16));
    mx = fmaxf(mx, __shfl_xor(mx, 32));

    // ---- defer-max: rescale only when max grew by > 8 (log2 domain) ----
    if (!__all(mx <= m_r + 8.f)) {
      float mnew = fmaxf(m_r, mx);
      float scn = exp2f(m_r - mnew);
      m_r = mnew;
      l_r *= scn;
#pragma unroll
      for (int r = 0; r < 4; ++r) {
        float scr = __shfl(scn, grp * 4 + r, 16);
#pragma unroll
        for (int ds = 0; ds < 4; ++ds) Oacc[ds][r] *= scr;
      }
    }

    // ---- P = exp2(S - m), packed in-lane as the PV A-frag (sigma order) ----
    union { bf16 hh[8]; bf16x8 v; } p0;
    float rsl = 0.f;
#pragma unroll
    for (int js = 0; js < 2; ++js)
#pragma unroll
      for (int r = 0; r < 4; ++r) {
        float p = exp2f(Sacc[js][r] - m_r);
        rsl += p;
        p0.hh[js * 4 + r] = (bf16)p;     // k-slot e = js*4 + r
      }
    l_r += rsl;

    // ---- O += P @ V : one K=32 MFMA per d-tile ----
    __builtin_amdgcn_s_setprio(1);
#pragma unroll
    for (int ds = 0; ds < 4; ++ds) {
      bf16x8 v0 = *(const bf16x8*)&Vt[cur][ds * 16 + ln][grp * 8];
      Oacc[ds] = MFMA16(p0.v, v0, Oacc[ds]);
    }
    __builtin_amdgcn_s_setprio(0);
  }

  // epilogue: finish l reduction across grp copies (rows = ln)
  l_r += __shfl_xor(l_r, 16);
  l_r += __shfl_xor(l_r, 32);

  int part = s * 128 + bh;
#pragma unroll
  for (int ds = 0; ds < 4; ++ds)
#pragma unroll
    for (int r = 0; r < 4; ++r) {
      int il = w * 16 + grp * 4 + r;
      Opart[((size_t)part * 128 + il) * 64 + ds * 16 + ln] = (bf16)Oacc[ds][r];
    }
  if (grp == 0) {
    mws[(size_t)part * 128 + iq] = m_r;
    lws[(size_t)part * 128 + iq] = l_r;
  }
}

// ============ split-K combine over 12 parts (LDS-staged m/l, exp2 domain) ============
__global__ __launch_bounds__(256) void k_combine(const bf16* __restrict__ Opart,
                                                 const float* __restrict__ mws,
                                                 const float* __restrict__ lws,
                                                 bf16* __restrict__ Aout) {
  __shared__ float msh[12][32], lsh[12][32];
  int bh = blockIdx.x, q = blockIdx.y, t = threadIdx.x;
  int b = bh >> 4, h = bh & 15;
  for (int idx = t; idx < 384; idx += 256) {
    int s = idx >> 5, io = idx & 31;
    msh[s][io] = mws[(size_t)(s * 128 + bh) * 128 + q * 32 + io];
    lsh[s][io] = lws[(size_t)(s * 128 + bh) * 128 + q * 32 + io];
  }
  __syncthreads();
  int dm = t & 63, i4 = t >> 6;
  for (int ii = 0; ii < 8; ++ii) {
    int io = i4 * 8 + ii;
    int i = q * 32 + io;
    float M = -1e30f;
#pragma unroll
    for (int s = 0; s < 12; ++s) M = fmaxf(M, msh[s][io]);
    float L = 0.f, acc = 0.f;
#pragma unroll
    for (int s = 0; s < 12; ++s) {
      float wgt = exp2f(msh[s][io] - M);
      L += wgt * lsh[s][io];
      acc += wgt * (float)Opart[((size_t)(s * 128 + bh) * 128 + i) * 64 + dm];
    }
    Aout[((size_t)(b * 128 + i)) * 1024 + h * 64 + dm] = (bf16)(acc / L);
  }
}

extern "C" void kernel_launch(void* const* d_in, const int* in_sizes, int n_in,
                              void* d_out, int out_size, void* d_ws, size_t ws_size,
                              hipStream_t stream) {
  (void)in_sizes; (void)n_in; (void)out_size; (void)ws_size;
  const float* X      = (const float*)d_in[0];
  const float* cacheK = (const float*)d_in[1];
  const float* cacheV = (const float*)d_in[2];
  const float* Wq     = (const float*)d_in[3];
  const float* bq     = (const float*)d_in[4];
  const float* Wk     = (const float*)d_in[5];
  const float* Wv     = (const float*)d_in[6];
  const float* Wproj  = (const float*)d_in[7];
  const float* bproj  = (const float*)d_in[8];
  const float* Wr     = (const float*)d_in[9];
  const float* br     = (const float*)d_in[10];
  const float* bnd    = (const float*)d_in[11];
  const float* lng    = (const float*)d_in[12];
  const float* lnb    = (const float*)d_in[13];
  float* out = (float*)d_out;

  char* ws = (char*)d_ws;
  bf16* Wt_all = (bf16*)ws;  ws += (size_t)3328 * 1024 * 2;
  bf16* Wpt    = (bf16*)ws;  ws += (size_t)1024 * 1024 * 2;
  bf16* Xn     = (bf16*)ws;  ws += (size_t)1024 * 1024 * 2;
  bf16* Qb     = (bf16*)ws;  ws += (size_t)1024 * 1024 * 2;
  bf16* Kn     = (bf16*)ws;  ws += (size_t)1024 * 1024 * 2;
  bf16* Vn     = (bf16*)ws;  ws += (size_t)1024 * 1024 * 2;
  bf16* Aattn  = (bf16*)ws;  ws += (size_t)1024 * 1024 * 2;
  float* Rws   = (float*)ws; ws += (size_t)128 * 128 * 10 * 4;
  float* mws   = (float*)ws; ws += (size_t)12 * 128 * 128 * 4;
  float* lws   = (float*)ws; ws += (size_t)12 * 128 * 128 * 4;
  bf16* Opart  = (bf16*)ws;  ws += (size_t)12 * 128 * 128 * 64 * 2;

  k_convert<<<dim3(68 * 16), 256, 0, stream>>>(Wq, Wk, Wv, Wr, Wproj, Wt_all, Wpt);
  k_ln<<<dim3(1024), 256, 0, stream>>>(X, lng, lnb, Xn);
  k_gemm<0><<<dim3(26, 8), 512, 0, stream>>>(Xn, Wt_all, Qb, Kn, Vn, Rws, bq, br,
                                             nullptr, nullptr, nullptr);
  k_attn<<<dim3(1536), 512, 0, stream>>>(cacheK, cacheV, Kn, Vn, Qb, Rws, bnd,
                                         Opart, mws, lws);
  k_combine<<<dim3(128, 4), 256, 0, stream>>>(Opart, mws, lws, Aattn);
  k_gemm<1><<<dim3(8, 8), 512, 0, stream>>>(Aattn, Wpt, nullptr, nullptr, nullptr,
                                            nullptr, nullptr, nullptr, out, bproj, X);
}